// Round 10
// baseline (93.210 us; speedup 1.0000x reference)
//
#include <hip/hip_runtime.h>

#define NODES 14
#define IN_F 24
#define HID1 32
#define HID2 64
#define OUT_F 24
#define SLOPE 0.2f

#define XS_S 28   // xs stride (float4-aligned)
#define H1_S 36   // h1s stride (float4-aligned)
#define H2_S 68   // h2s stride

// u-vector layout in d_ws: us1[48] ud1[48] us2[64] ud2[64]  (224 floats)
#define U_US1 0
#define U_UD1 48
#define U_US2 96
#define U_UD2 160
#define U_TOT 224

#define PHASE_FENCE() __builtin_amdgcn_sched_barrier(0)

// ---- kernel 1: precompute u = W @ a  (graph-invariant, once) ----
__global__ __launch_bounds__(256) void compute_uvecs(
    const float* __restrict__ W1, const float* __restrict__ a_src1,
    const float* __restrict__ a_dst1,
    const float* __restrict__ W2, const float* __restrict__ a_src2,
    const float* __restrict__ a_dst2, float* __restrict__ u)
{
  const int tid = threadIdx.x;
  if (tid < 96) {
    const int sd = (tid >= 48), r = tid - sd * 48;
    const int h = (r >= IN_F), k = r - h * IN_F;
    const float* av = sd ? a_dst1 : a_src1;
    float s = 0.f;
#pragma unroll
    for (int f = 0; f < HID1; ++f)
      s += W1[k * 64 + h * HID1 + f] * av[h * HID1 + f];
    u[(sd ? U_UD1 : U_US1) + h * IN_F + k] = s;
  } else if (tid < 224) {
    const int j = tid - 96;
    const int sd = (j >= 64), r = j - sd * 64;
    const int h = (r >= HID1), k = r - h * HID1;
    const float* av = sd ? a_dst2 : a_src2;
    float s = 0.f;
#pragma unroll
    for (int f = 0; f < HID2; ++f)
      s += W2[k * 128 + h * HID2 + f] * av[h * HID2 + f];
    u[(sd ? U_UD2 : U_US2) + h * HID1 + k] = s;
  }
}

// ---- kernel 2: fused GNN+MLP, one graph per 256-thread (4-wave) block ----
// Design targets VGPR <= 64 (m69 cliff: 8 waves/SIMD) so the grid's full
// 32 waves/CU can be resident. No duplicated work (R9 lesson), no LDS
// round-trip for GEMM fragments (R8 lesson): each lane owns 2 columns x a
// node-group in registers; aggregates combine via intra-wave shfl_xor with
// heads summed BEFORE the shuffle. logits+softmax ride in wave 0's stream
// (wave-internal LDS ordering). 7 barriers vs R7's 9. Fences stop
// cross-phase hoisting (R6) without forcing a cap (R4/R5).
__global__ __launch_bounds__(256) void gnn_fused(
    const float* __restrict__ x, const float* __restrict__ y,
    const float* __restrict__ W1, const float* __restrict__ b1,
    const float* __restrict__ W2, const float* __restrict__ b2,
    const float* __restrict__ Wf1, const float* __restrict__ bf1,
    const float* __restrict__ Wf2, const float* __restrict__ bf2,
    const float* __restrict__ uvec,
    float* __restrict__ out, int ngraphs)
{
  const int g = blockIdx.x;
  const int tid = threadIdx.x;
  const int lane = tid & 63;
  const int wv = tid >> 6;

  __shared__ float u[U_TOT];                         // 224
  __shared__ __align__(16) float xs[NODES * XS_S];   // 392
  __shared__ float als[28], ald[28];
  __shared__ float watt[NODES * 28];                 // [i][j*2+h]
  __shared__ __align__(16) float h1s[NODES * H1_S];  // 504
  __shared__ float h2s[NODES * H2_S];                // 952
  __shared__ float hhs[112];

  // ---- S: stage (y-copy, xs, u) ----
  if (tid < (NODES * OUT_F) / 4) {                   // 84 float4
    const float4* y4 = (const float4*)(y + (size_t)g * (NODES * OUT_F));
    float4* o4 = (float4*)(out + (size_t)NODES * ngraphs * OUT_F
                               + (size_t)g * (NODES * OUT_F));
    o4[tid] = y4[tid];
  } else if (tid < 168) {                            // 84 float4 -> xs
    const int idx = tid - 84;
    const float4 v = *(const float4*)(x + (size_t)g * (NODES * IN_F) + idx * 4);
    const int n = (idx * 4) / IN_F, k = (idx * 4) - n * IN_F;
    *(float4*)&xs[n * XS_S + k] = v;
  }
  if (tid < U_TOT) u[tid] = uvec[tid];
  __syncthreads();
  PHASE_FENCE();

  // ---- P1: wave0 = logits1 + softmax1 (wave-internal); all = GEMM1 ----
  if (wv == 0) {
    if (lane < 56) {
      const int n = lane >> 2, h = (lane >> 1) & 1, sd = lane & 1;
      const float* uu = u + (sd ? U_UD1 : U_US1) + h * IN_F;
      float s = 0.f;
#pragma unroll
      for (int k = 0; k < IN_F; ++k) s += xs[n * XS_S + k] * uu[k];
      (sd ? ald : als)[n * 2 + h] = s;
    }
    if (lane < NODES * 2) {
      const int h = lane & 1;
      const float ad = ald[lane];
      float a[NODES]; float m = -1e30f;
#pragma unroll
      for (int i = 0; i < NODES; ++i) {
        float v = als[i * 2 + h] + ad;
        v = v > 0.f ? v : SLOPE * v;
        a[i] = v; m = fmaxf(m, v);
      }
      float den = 0.f;
#pragma unroll
      for (int i = 0; i < NODES; ++i) { a[i] = __expf(a[i] - m); den += a[i]; }
      const float r = 1.f / den;
#pragma unroll
      for (int i = 0; i < NODES; ++i) watt[i * 28 + lane] = a[i] * r;
    }
  }
  // GEMM1: lane owns cols {f8, 32+f8} x nodes {2*g8, 2*g8+1}
  const int f8 = (wv << 3) | (lane & 7);   // [0,32)
  const int g8 = lane >> 3;                // 0..7 (g8==7 -> no nodes)
  float xc[2][2] = {{0.f, 0.f}, {0.f, 0.f}};
  if (g8 < 7) {
#pragma unroll
    for (int c = 0; c < 2; ++c) {
      const int col = c * HID1 + f8;
      float wr[IN_F];
#pragma unroll
      for (int k = 0; k < IN_F; ++k) wr[k] = W1[k * 64 + col];
#pragma unroll
      for (int t = 0; t < 2; ++t) {
        const int n = g8 * 2 + t;
        float acc = 0.f;
#pragma unroll
        for (int k4 = 0; k4 < IN_F / 4; ++k4) {
          const float4 xv = *(const float4*)&xs[n * XS_S + k4 * 4];
          acc += xv.x * wr[k4 * 4 + 0] + xv.y * wr[k4 * 4 + 1]
               + xv.z * wr[k4 * 4 + 2] + xv.w * wr[k4 * 4 + 3];
        }
        xc[c][t] = acc;
      }
      PHASE_FENCE();   // force wr re-use between the two columns
    }
  }
  __syncthreads();
  PHASE_FENCE();

  // ---- P2: agg1 — per-lane partials over its 2 nodes, shfl combine ----
  {
    float q[NODES];
#pragma unroll
    for (int n = 0; n < NODES; ++n) {
      float s = 0.f;
      if (g8 < 7) {
#pragma unroll
        for (int t = 0; t < 2; ++t) {
          const int i = g8 * 2 + t;
          const float2 wv2 = *(const float2*)&watt[i * 28 + n * 2];
          s += wv2.x * xc[0][t] + wv2.y * xc[1][t];
        }
      }
      q[n] = s;
    }
#pragma unroll
    for (int n = 0; n < NODES; ++n) q[n] += __shfl_xor(q[n], 8);
#pragma unroll
    for (int n = 0; n < NODES; ++n) q[n] += __shfl_xor(q[n], 16);
#pragma unroll
    for (int n = 0; n < NODES; ++n) q[n] += __shfl_xor(q[n], 32);
    if (g8 < 7) {
      const float bb = b1[f8];
#pragma unroll
      for (int t = 0; t < 2; ++t) {
        const int n = g8 * 2 + t;
        const float v = 0.5f * q[n] + bb;
        h1s[n * H1_S + f8] = v > 0.f ? v : expm1f(v);
      }
    }
  }
  __syncthreads();
  PHASE_FENCE();

  // ---- P3: wave0 = logits2 + softmax2; all = GEMM2 ----
  if (wv == 0) {
    if (lane < 56) {
      const int n = lane >> 2, h = (lane >> 1) & 1, sd = lane & 1;
      const float* uu = u + (sd ? U_UD2 : U_US2) + h * HID1;
      float s = 0.f;
#pragma unroll
      for (int k = 0; k < HID1; ++k) s += h1s[n * H1_S + k] * uu[k];
      (sd ? ald : als)[n * 2 + h] = s;
    }
    if (lane < NODES * 2) {
      const int h = lane & 1;
      const float ad = ald[lane];
      float a[NODES]; float m = -1e30f;
#pragma unroll
      for (int i = 0; i < NODES; ++i) {
        float v = als[i * 2 + h] + ad;
        v = v > 0.f ? v : SLOPE * v;
        a[i] = v; m = fmaxf(m, v);
      }
      float den = 0.f;
#pragma unroll
      for (int i = 0; i < NODES; ++i) { a[i] = __expf(a[i] - m); den += a[i]; }
      const float r = 1.f / den;
#pragma unroll
      for (int i = 0; i < NODES; ++i) watt[i * 28 + lane] = a[i] * r;
    }
  }
  // GEMM2: lane owns cols {f16, 64+f16} x nodes {4*g4 .. 4*g4+3}
  const int f16 = (wv << 4) | (lane & 15);  // [0,64)
  const int g4 = lane >> 4;                 // 0..3
  const int nb = g4 * 4;
  float x2[2][4] = {{0.f,0.f,0.f,0.f},{0.f,0.f,0.f,0.f}};
#pragma unroll
  for (int c = 0; c < 2; ++c) {
    const int col = c * HID2 + f16;
    float w2[HID1];
#pragma unroll
    for (int k = 0; k < HID1; ++k) w2[k] = W2[k * 128 + col];
#pragma unroll
    for (int t = 0; t < 4; ++t) {
      const int n = nb + t;
      if (n < NODES) {
        float acc = 0.f;
#pragma unroll
        for (int k4 = 0; k4 < HID1 / 4; ++k4) {
          const float4 hv = *(const float4*)&h1s[n * H1_S + k4 * 4];
          acc += hv.x * w2[k4 * 4 + 0] + hv.y * w2[k4 * 4 + 1]
               + hv.z * w2[k4 * 4 + 2] + hv.w * w2[k4 * 4 + 3];
        }
        x2[c][t] = acc;
      }
    }
    PHASE_FENCE();   // force w2 re-use between the two columns
  }
  __syncthreads();
  PHASE_FENCE();

  // ---- P4: agg2 — partials over 4 nodes, shfl combine, write h2s ----
  {
    float q2[NODES];
#pragma unroll
    for (int n = 0; n < NODES; ++n) {
      float s = 0.f;
#pragma unroll
      for (int t = 0; t < 4; ++t) {
        const int i = nb + t;
        if (i < NODES) {
          const float2 wv2 = *(const float2*)&watt[i * 28 + n * 2];
          s += wv2.x * x2[0][t] + wv2.y * x2[1][t];
        }
      }
      q2[n] = s;
    }
#pragma unroll
    for (int n = 0; n < NODES; ++n) q2[n] += __shfl_xor(q2[n], 16);
#pragma unroll
    for (int n = 0; n < NODES; ++n) q2[n] += __shfl_xor(q2[n], 32);
    const float bb = b2[f16];
#pragma unroll
    for (int t = 0; t < 4; ++t) {
      const int n = nb + t;
      if (n < NODES) h2s[n * H2_S + f16] = 0.5f * q2[n] + bb;
    }
  }
  __syncthreads();
  PHASE_FENCE();

  // ---- P5: MLP1 — 112 items x 2 half-dots (224 lanes) ----
  if (tid < 224) {
    const int item = tid >> 1, k = item >> 3, e = item & 7, hf = tid & 1;
    float s = 0.f;
#pragma unroll
    for (int f = 0; f < 32; ++f)
      s += h2s[k * H2_S + hf * 32 + f] * Wf1[(k * HID2 + hf * 32 + f) * 8 + e];
    const float ss = __shfl_xor(s, 1);
    if (hf == 0) hhs[item] = fmaxf(s + ss + bf1[k * 8 + e], 0.f);
  }
  __syncthreads();
  PHASE_FENCE();

  // ---- P6: MLP2 (336 outputs) ----
  for (int idx = tid; idx < NODES * OUT_F; idx += 256) {
    const int k = idx / OUT_F, o = idx - k * OUT_F;
    float acc = bf2[k * OUT_F + o];
#pragma unroll
    for (int e = 0; e < 8; ++e)
      acc += hhs[k * 8 + e] * Wf2[(k * 8 + e) * OUT_F + o];
    out[(size_t)k * ngraphs * OUT_F + (size_t)g * OUT_F + o] =
        1.f / (1.f + __expf(-acc));
  }
}

extern "C" void kernel_launch(void* const* d_in, const int* in_sizes, int n_in,
                              void* d_out, int out_size, void* d_ws, size_t ws_size,
                              hipStream_t stream) {
  const float* x      = (const float*)d_in[0];
  const float* y      = (const float*)d_in[1];
  // d_in[2] = edge_index, d_in[3] = batch : structure fixed, unused
  const float* W1     = (const float*)d_in[4];
  const float* a_src1 = (const float*)d_in[5];
  const float* a_dst1 = (const float*)d_in[6];
  const float* b1     = (const float*)d_in[7];
  const float* W2     = (const float*)d_in[8];
  const float* a_src2 = (const float*)d_in[9];
  const float* a_dst2 = (const float*)d_in[10];
  const float* b2     = (const float*)d_in[11];
  const float* Wf1    = (const float*)d_in[12];
  const float* bf1    = (const float*)d_in[13];
  const float* Wf2    = (const float*)d_in[14];
  const float* bf2    = (const float*)d_in[15];
  float* out = (float*)d_out;
  float* u   = (float*)d_ws;

  const int nnodes  = in_sizes[0] / IN_F;
  const int ngraphs = nnodes / NODES;

  hipLaunchKernelGGL(compute_uvecs, dim3(1), dim3(256), 0, stream,
                     W1, a_src1, a_dst1, W2, a_src2, a_dst2, u);
  hipLaunchKernelGGL(gnn_fused, dim3(ngraphs), dim3(256), 0, stream,
                     x, y, W1, b1, W2, b2, Wf1, bf1, Wf2, bf2, u, out, ngraphs);
}

// Round 11
// 31.262 us; speedup vs baseline: 2.9816x; 2.9816x over previous
//
#include <hip/hip_runtime.h>

#define NODES 14
#define IN_F 24
#define HID1 32
#define HID2 64
#define OUT_F 24
#define SLOPE 0.2f

#define XS_S 28   // xs stride   (float4-aligned)
#define H1_S 36   // h1s stride  (float4-aligned)
#define H2_S 68   // h2s stride

// u-vector layout in d_ws: us1[48] ud1[48] us2[64] ud2[64]  (224 floats)
#define U_US1 0
#define U_UD1 48
#define U_US2 96
#define U_UD2 160
#define U_TOT 224

#define PHASE_FENCE() __builtin_amdgcn_sched_barrier(0)

// ---- kernel 1: precompute u = W @ a  (graph-invariant, once) ----
__global__ __launch_bounds__(256) void compute_uvecs(
    const float* __restrict__ W1, const float* __restrict__ a_src1,
    const float* __restrict__ a_dst1,
    const float* __restrict__ W2, const float* __restrict__ a_src2,
    const float* __restrict__ a_dst2, float* __restrict__ u)
{
  const int tid = threadIdx.x;
  if (tid < 96) {
    const int sd = (tid >= 48), r = tid - sd * 48;
    const int h = (r >= IN_F), k = r - h * IN_F;
    const float* av = sd ? a_dst1 : a_src1;
    float s = 0.f;
#pragma unroll
    for (int f = 0; f < HID1; ++f)
      s += W1[k * 64 + h * HID1 + f] * av[h * HID1 + f];
    u[(sd ? U_UD1 : U_US1) + h * IN_F + k] = s;
  } else if (tid < 224) {
    const int j = tid - 96;
    const int sd = (j >= 64), r = j - sd * 64;
    const int h = (r >= HID1), k = r - h * HID1;
    const float* av = sd ? a_dst2 : a_src2;
    float s = 0.f;
#pragma unroll
    for (int f = 0; f < HID2; ++f)
      s += W2[k * 128 + h * HID2 + f] * av[h * HID2 + f];
    u[(sd ? U_UD2 : U_US2) + h * HID1 + k] = s;
  }
}

// ---- kernel 2: fused GNN+MLP, one graph per 128-thread block ----
// R7 structure (best measured: 31.5us) with two squeezes:
//  * logits+softmax merged into the GEMM phases (wave0-internal ordering;
//    validated by R10's pass) -> 9 barriers down to 7
//  * weight-load bursts issued one phase early (W1 in stage, W2 end of
//    phase1 with col=tid -- R9's bug was col=lane --, Wf1-half end of ph3)
// Fences at phase boundaries keep the compiler from re-inflating liveness
// (R6: unfenced -> VGPR 256; R4/R5: forced cap -> 1 GB spills).
__global__ __launch_bounds__(128) void gnn_fused(
    const float* __restrict__ x, const float* __restrict__ y,
    const float* __restrict__ W1, const float* __restrict__ b1,
    const float* __restrict__ W2, const float* __restrict__ b2,
    const float* __restrict__ Wf1, const float* __restrict__ bf1,
    const float* __restrict__ Wf2, const float* __restrict__ bf2,
    const float* __restrict__ uvec,
    float* __restrict__ out, int ngraphs)
{
  const int g = blockIdx.x;
  const int tid = threadIdx.x;
  const int lane = tid & 63;
  const int wid = tid >> 6;

  __shared__ float u[U_TOT];                         // 224
  __shared__ __align__(16) float xs[NODES * XS_S];   // 392
  __shared__ __align__(16) float h1s[NODES * H1_S];  // 504
  __shared__ float h2s[NODES * H2_S];                // 952
  __shared__ float watt[NODES * 28];                 // [i][j*2+h]
  __shared__ float als[28], ald[28];
  __shared__ float hhs[112];

  // ---- P0 stage: W1 prefetch + y-copy + xs + u ----
  float w1r[IN_F];
#pragma unroll
  for (int k = 0; k < IN_F; ++k) w1r[k] = W1[k * 64 + lane];

  if (tid < (NODES * OUT_F) / 4) {
    const float4* y4 = (const float4*)(y + (size_t)g * (NODES * OUT_F));
    float4* o4 = (float4*)(out + (size_t)NODES * ngraphs * OUT_F
                               + (size_t)g * (NODES * OUT_F));
    o4[tid] = y4[tid];
  }
  for (int i = tid; i < U_TOT; i += 128) u[i] = uvec[i];
  if (tid < (NODES * IN_F) / 4) {
    const float4 v = *(const float4*)(x + (size_t)g * (NODES * IN_F) + tid * 4);
    const int n = (tid * 4) / IN_F, k = (tid * 4) - n * IN_F;
    *(float4*)&xs[n * XS_S + k] = v;
  }
  __syncthreads();              // B0
  PHASE_FENCE();

  // ---- P1: GEMM1 (col=lane, both waves) ; wave0 += logits1+softmax1 ----
  float xcol[NODES];
  {
#pragma unroll 2
    for (int n = 0; n < NODES; ++n) {
      float acc = 0.f;
#pragma unroll
      for (int k4 = 0; k4 < IN_F / 4; ++k4) {
        const float4 xv = *(const float4*)&xs[n * XS_S + k4 * 4];
        acc += xv.x * w1r[k4 * 4 + 0] + xv.y * w1r[k4 * 4 + 1]
             + xv.z * w1r[k4 * 4 + 2] + xv.w * w1r[k4 * 4 + 3];
      }
      xcol[n] = acc;
    }
  }
  PHASE_FENCE();
  if (wid == 0) {
    if (lane < 56) {            // logits1: al[n,h] = x[n,:].u1[h,:]
      const int n = lane >> 2, h = (lane >> 1) & 1, sd = lane & 1;
      const float* uu = u + (sd ? U_UD1 : U_US1) + h * IN_F;
      float s = 0.f;
#pragma unroll
      for (int k = 0; k < IN_F; ++k) s += xs[n * XS_S + k] * uu[k];
      (sd ? ald : als)[n * 2 + h] = s;
    }
    if (lane < NODES * 2) {     // softmax1 (wave0-internal dep on als/ald)
      const int h = lane & 1;
      const float ad = ald[lane];
      float a[NODES]; float m = -1e30f;
#pragma unroll
      for (int i = 0; i < NODES; ++i) {
        float v = als[i * 2 + h] + ad;
        v = v > 0.f ? v : SLOPE * v;
        a[i] = v; m = fmaxf(m, v);
      }
      float den = 0.f;
#pragma unroll
      for (int i = 0; i < NODES; ++i) { a[i] = __expf(a[i] - m); den += a[i]; }
      const float r = 1.f / den;
#pragma unroll
      for (int i = 0; i < NODES; ++i) watt[i * 28 + lane] = a[i] * r;
    }
  }
  // W2 prefetch for GEMM2 (col = tid), issued before the barrier wait
  float w2r[HID1];
#pragma unroll
  for (int k = 0; k < HID1; ++k) w2r[k] = W2[k * 128 + tid];
  __syncthreads();              // B1: watt + xcol ready
  PHASE_FENCE();

  // ---- P2: agg1 — wave wid does nodes [7w,7w+7); head-mean+bias+ELU ----
  {
    const int h = lane >> 5, f5 = lane & 31;
    const float bb = b1[f5];
#pragma unroll 2
    for (int tt = 0; tt < NODES / 2; ++tt) {
      const int n = wid * (NODES / 2) + tt;
      float o = 0.f;
#pragma unroll
      for (int i = 0; i < NODES; ++i)
        o += watt[i * 28 + n * 2 + h] * xcol[i];
      const float oo = __shfl_xor(o, 32);
      if (h == 0) {
        const float v = 0.5f * (o + oo) + bb;
        h1s[n * H1_S + f5] = v > 0.f ? v : expm1f(v);
      }
    }
  }
  __syncthreads();              // B2: h1s ready
  PHASE_FENCE();

  // ---- P3: GEMM2 (col=tid, w2r prefetched) ; wave0 += logits2+softmax2 ----
  float x2c[NODES];
  {
#pragma unroll 2
    for (int n = 0; n < NODES; ++n) {
      float acc = 0.f;
#pragma unroll
      for (int k4 = 0; k4 < HID1 / 4; ++k4) {
        const float4 hv = *(const float4*)&h1s[n * H1_S + k4 * 4];
        acc += hv.x * w2r[k4 * 4 + 0] + hv.y * w2r[k4 * 4 + 1]
             + hv.z * w2r[k4 * 4 + 2] + hv.w * w2r[k4 * 4 + 3];
      }
      x2c[n] = acc;
    }
  }
  PHASE_FENCE();
  if (wid == 0) {
    if (lane < 56) {            // logits2
      const int n = lane >> 2, h = (lane >> 1) & 1, sd = lane & 1;
      const float* uu = u + (sd ? U_UD2 : U_US2) + h * HID1;
      float s = 0.f;
#pragma unroll
      for (int k = 0; k < HID1; ++k) s += h1s[n * H1_S + k] * uu[k];
      (sd ? ald : als)[n * 2 + h] = s;
    }
    if (lane < NODES * 2) {     // softmax2
      const int h = lane & 1;
      const float ad = ald[lane];
      float a[NODES]; float m = -1e30f;
#pragma unroll
      for (int i = 0; i < NODES; ++i) {
        float v = als[i * 2 + h] + ad;
        v = v > 0.f ? v : SLOPE * v;
        a[i] = v; m = fmaxf(m, v);
      }
      float den = 0.f;
#pragma unroll
      for (int i = 0; i < NODES; ++i) { a[i] = __expf(a[i] - m); den += a[i]; }
      const float r = 1.f / den;
#pragma unroll
      for (int i = 0; i < NODES; ++i) watt[i * 28 + lane] = a[i] * r;
    }
  }
  // Wf1 first-half prefetch for MLP1 (112 lanes), issued before barrier
  float wf[32];
  if (tid < NODES * 8) {
    const int k = tid >> 3, e = tid & 7;
#pragma unroll
    for (int f = 0; f < 32; ++f) wf[f] = Wf1[(k * HID2 + f) * 8 + e];
  }
  __syncthreads();              // B3: watt + x2c ready
  PHASE_FENCE();

  // ---- P4: agg2 — head=wid; cross-wave combine via LDS ----
  {
    float agg[NODES];
#pragma unroll
    for (int n = 0; n < NODES; ++n) {
      float o = 0.f;
#pragma unroll
      for (int i = 0; i < NODES; ++i)
        o += watt[i * 28 + n * 2 + wid] * x2c[i];
      agg[n] = o;
    }
    if (wid == 1) {
#pragma unroll
      for (int n = 0; n < NODES; ++n) h2s[n * H2_S + lane] = agg[n];
    }
    __syncthreads();            // B4
    if (wid == 0) {
      const float bb = b2[lane];
#pragma unroll
      for (int n = 0; n < NODES; ++n)
        h2s[n * H2_S + lane] = 0.5f * (agg[n] + h2s[n * H2_S + lane]) + bb;
    }
  }
  __syncthreads();              // B5: h2s ready
  PHASE_FENCE();

  // ---- P5: MLP1 (112 lanes; first 32 f's from prefetched wf) ----
  if (tid < NODES * 8) {
    const int k = tid >> 3, e = tid & 7;
    float acc = bf1[k * 8 + e];
#pragma unroll
    for (int f = 0; f < 32; ++f)
      acc += h2s[k * H2_S + f] * wf[f];
#pragma unroll 8
    for (int f = 32; f < HID2; ++f)
      acc += h2s[k * H2_S + f] * Wf1[(k * HID2 + f) * 8 + e];
    hhs[tid] = fmaxf(acc, 0.f);
  }
  __syncthreads();              // B6: hhs ready
  PHASE_FENCE();

  // ---- P6: MLP2 (336 outputs) ----
  for (int idx = tid; idx < NODES * OUT_F; idx += 128) {
    const int k = idx / OUT_F, o = idx - k * OUT_F;
    float acc = bf2[k * OUT_F + o];
#pragma unroll
    for (int e = 0; e < 8; ++e)
      acc += hhs[k * 8 + e] * Wf2[(k * 8 + e) * OUT_F + o];
    out[(size_t)k * ngraphs * OUT_F + (size_t)g * OUT_F + o] =
        1.f / (1.f + __expf(-acc));
  }
}

extern "C" void kernel_launch(void* const* d_in, const int* in_sizes, int n_in,
                              void* d_out, int out_size, void* d_ws, size_t ws_size,
                              hipStream_t stream) {
  const float* x      = (const float*)d_in[0];
  const float* y      = (const float*)d_in[1];
  // d_in[2] = edge_index, d_in[3] = batch : structure fixed, unused
  const float* W1     = (const float*)d_in[4];
  const float* a_src1 = (const float*)d_in[5];
  const float* a_dst1 = (const float*)d_in[6];
  const float* b1     = (const float*)d_in[7];
  const float* W2     = (const float*)d_in[8];
  const float* a_src2 = (const float*)d_in[9];
  const float* a_dst2 = (const float*)d_in[10];
  const float* b2     = (const float*)d_in[11];
  const float* Wf1    = (const float*)d_in[12];
  const float* bf1    = (const float*)d_in[13];
  const float* Wf2    = (const float*)d_in[14];
  const float* bf2    = (const float*)d_in[15];
  float* out = (float*)d_out;
  float* u   = (float*)d_ws;

  const int nnodes  = in_sizes[0] / IN_F;
  const int ngraphs = nnodes / NODES;

  hipLaunchKernelGGL(compute_uvecs, dim3(1), dim3(256), 0, stream,
                     W1, a_src1, a_dst1, W2, a_src2, a_dst2, u);
  hipLaunchKernelGGL(gnn_fused, dim3(ngraphs), dim3(128), 0, stream,
                     x, y, W1, b1, W2, b2, Wf1, bf1, Wf2, bf2, u, out, ngraphs);
}

// Round 12
// 29.829 us; speedup vs baseline: 3.1248x; 1.0480x over previous
//
#include <hip/hip_runtime.h>

#define NODES 14
#define IN_F 24
#define HID1 32
#define HID2 64
#define OUT_F 24
#define SLOPE 0.2f

#define XS_S 28   // xs stride   (float4-aligned: 112 B)
#define H1_S 36   // h1s stride  (float4-aligned: 144 B)
#define H2_S 68   // h2s stride  (float4-aligned: 272 B)

// u-vector layout in d_ws: us1[48] ud1[48] us2[64] ud2[64]  (224 floats)
#define U_US1 0
#define U_UD1 48
#define U_US2 96
#define U_UD2 160

#define PHASE_FENCE() __builtin_amdgcn_sched_barrier(0)

// ---- kernel 1: precompute u = W @ a  (graph-invariant, once) ----
__global__ __launch_bounds__(256) void compute_uvecs(
    const float* __restrict__ W1, const float* __restrict__ a_src1,
    const float* __restrict__ a_dst1,
    const float* __restrict__ W2, const float* __restrict__ a_src2,
    const float* __restrict__ a_dst2, float* __restrict__ u)
{
  const int tid = threadIdx.x;
  if (tid < 96) {
    const int sd = (tid >= 48), r = tid - sd * 48;
    const int h = (r >= IN_F), k = r - h * IN_F;
    const float* av = sd ? a_dst1 : a_src1;
    float s = 0.f;
#pragma unroll
    for (int f = 0; f < HID1; ++f)
      s += W1[k * 64 + h * HID1 + f] * av[h * HID1 + f];
    u[(sd ? U_UD1 : U_US1) + h * IN_F + k] = s;
  } else if (tid < 224) {
    const int j = tid - 96;
    const int sd = (j >= 64), r = j - sd * 64;
    const int h = (r >= HID1), k = r - h * HID1;
    const float* av = sd ? a_dst2 : a_src2;
    float s = 0.f;
#pragma unroll
    for (int f = 0; f < HID2; ++f)
      s += W2[k * 128 + h * HID2 + f] * av[h * HID2 + f];
    u[(sd ? U_UD2 : U_US2) + h * HID1 + k] = s;
  }
}

// ---- kernel 2: fused GNN+MLP, one graph per 128-thread block ----
// R11 skeleton; R12 cuts LDS-pipe instructions ~2x (the measured
// bottleneck: ~10K LDS cycles/graph x 8 graphs/CU ~= the 31us duration):
//  * attention weights transposed: wt[(dst*2+h)*16 + i] -- softmax writes
//    vectorized, aggregate reads become float4 broadcasts
//  * MLP1/MLP2 LDS reads vectorized (b128)
//  * u LDS staging dropped (logits read uvec from global/L2 as float4)
__global__ __launch_bounds__(128) void gnn_fused(
    const float* __restrict__ x, const float* __restrict__ y,
    const float* __restrict__ W1, const float* __restrict__ b1,
    const float* __restrict__ W2, const float* __restrict__ b2,
    const float* __restrict__ Wf1, const float* __restrict__ bf1,
    const float* __restrict__ Wf2, const float* __restrict__ bf2,
    const float* __restrict__ uvec,
    float* __restrict__ out, int ngraphs)
{
  const int g = blockIdx.x;
  const int tid = threadIdx.x;
  const int lane = tid & 63;
  const int wid = tid >> 6;

  __shared__ __align__(16) float xs[NODES * XS_S];   // 392
  __shared__ __align__(16) float h1s[NODES * H1_S];  // 504
  __shared__ __align__(16) float h2s[NODES * H2_S];  // 952
  __shared__ __align__(16) float wt[28 * 16];        // 448 [(dst*2+h)][i]
  __shared__ float als[28], ald[28];
  __shared__ __align__(16) float hhs[112];

  // ---- P0 stage: W1 prefetch + u1-row prefetch (wave0) + y + xs ----
  float w1r[IN_F];
#pragma unroll
  for (int k = 0; k < IN_F; ++k) w1r[k] = W1[k * 64 + lane];

  float4 u1v[6];                 // wave0 lanes<56: u1 row for logits1
  if (wid == 0 && lane < 56) {
    const int h = (lane >> 1) & 1, sd = lane & 1;
    const float* uu = uvec + (sd ? U_UD1 : U_US1) + h * IN_F;
#pragma unroll
    for (int k4 = 0; k4 < 6; ++k4) u1v[k4] = *(const float4*)&uu[k4 * 4];
  }

  if (tid < (NODES * OUT_F) / 4) {
    const float4* y4 = (const float4*)(y + (size_t)g * (NODES * OUT_F));
    float4* o4 = (float4*)(out + (size_t)NODES * ngraphs * OUT_F
                               + (size_t)g * (NODES * OUT_F));
    o4[tid] = y4[tid];
  }
  if (tid < (NODES * IN_F) / 4) {
    const float4 v = *(const float4*)(x + (size_t)g * (NODES * IN_F) + tid * 4);
    const int n = (tid * 4) / IN_F, k = (tid * 4) - n * IN_F;
    *(float4*)&xs[n * XS_S + k] = v;
  }
  __syncthreads();              // B0
  PHASE_FENCE();

  // ---- P1: GEMM1 (col=lane, both waves) ; wave0 += logits1+softmax1 ----
  float xcol[NODES];
  {
#pragma unroll 2
    for (int n = 0; n < NODES; ++n) {
      float acc = 0.f;
#pragma unroll
      for (int k4 = 0; k4 < IN_F / 4; ++k4) {
        const float4 xv = *(const float4*)&xs[n * XS_S + k4 * 4];
        acc += xv.x * w1r[k4 * 4 + 0] + xv.y * w1r[k4 * 4 + 1]
             + xv.z * w1r[k4 * 4 + 2] + xv.w * w1r[k4 * 4 + 3];
      }
      xcol[n] = acc;
    }
  }
  PHASE_FENCE();
  if (wid == 0) {
    if (lane < 56) {            // logits1: al[n,h] = x[n,:].u1[h,:]
      const int n = lane >> 2, sd = lane & 1;
      float s = 0.f;
#pragma unroll
      for (int k4 = 0; k4 < 6; ++k4) {
        const float4 xv = *(const float4*)&xs[n * XS_S + k4 * 4];
        s += xv.x * u1v[k4].x + xv.y * u1v[k4].y
           + xv.z * u1v[k4].z + xv.w * u1v[k4].w;
      }
      (sd ? ald : als)[((lane >> 2) << 1) | ((lane >> 1) & 1)] = s;
      (void)n;
    }
    if (lane < NODES * 2) {     // softmax1 -> transposed wt writes
      const int h = lane & 1;
      const float ad = ald[lane];
      float a[NODES]; float m = -1e30f;
#pragma unroll
      for (int i = 0; i < NODES; ++i) {
        float v = als[i * 2 + h] + ad;
        v = v > 0.f ? v : SLOPE * v;
        a[i] = v; m = fmaxf(m, v);
      }
      float den = 0.f;
#pragma unroll
      for (int i = 0; i < NODES; ++i) { a[i] = __expf(a[i] - m); den += a[i]; }
      const float r = 1.f / den;
      float* wr = &wt[lane * 16];
      *(float4*)&wr[0]  = make_float4(a[0]*r,  a[1]*r,  a[2]*r,  a[3]*r);
      *(float4*)&wr[4]  = make_float4(a[4]*r,  a[5]*r,  a[6]*r,  a[7]*r);
      *(float4*)&wr[8]  = make_float4(a[8]*r,  a[9]*r,  a[10]*r, a[11]*r);
      *(float2*)&wr[12] = make_float2(a[12]*r, a[13]*r);
    }
  }
  // W2 prefetch for GEMM2 (col = tid), issued before the barrier wait
  float w2r[HID1];
#pragma unroll
  for (int k = 0; k < HID1; ++k) w2r[k] = W2[k * 128 + tid];
  __syncthreads();              // B1: wt + xcol ready
  PHASE_FENCE();

  // ---- P2: agg1 — wave wid does nodes [7w,7w+7); float4 wt broadcasts ----
  {
    const int h = lane >> 5, f5 = lane & 31;
    const float bb = b1[f5];
#pragma unroll 2
    for (int tt = 0; tt < NODES / 2; ++tt) {
      const int n = wid * (NODES / 2) + tt;
      const float* wr = &wt[(n * 2 + h) * 16];
      const float4 w0 = *(const float4*)&wr[0];
      const float4 w1 = *(const float4*)&wr[4];
      const float4 w2 = *(const float4*)&wr[8];
      const float2 w3 = *(const float2*)&wr[12];
      float o = w0.x*xcol[0] + w0.y*xcol[1] + w0.z*xcol[2] + w0.w*xcol[3]
              + w1.x*xcol[4] + w1.y*xcol[5] + w1.z*xcol[6] + w1.w*xcol[7]
              + w2.x*xcol[8] + w2.y*xcol[9] + w2.z*xcol[10] + w2.w*xcol[11]
              + w3.x*xcol[12] + w3.y*xcol[13];
      const float oo = __shfl_xor(o, 32);
      if (h == 0) {
        const float v = 0.5f * (o + oo) + bb;
        h1s[n * H1_S + f5] = v > 0.f ? v : expm1f(v);
      }
    }
  }
  __syncthreads();              // B2: h1s ready
  PHASE_FENCE();

  // ---- P3: GEMM2 (col=tid, w2r prefetched) ; wave0 += logits2+softmax2 ----
  float x2c[NODES];
  {
#pragma unroll 2
    for (int n = 0; n < NODES; ++n) {
      float acc = 0.f;
#pragma unroll
      for (int k4 = 0; k4 < HID1 / 4; ++k4) {
        const float4 hv = *(const float4*)&h1s[n * H1_S + k4 * 4];
        acc += hv.x * w2r[k4 * 4 + 0] + hv.y * w2r[k4 * 4 + 1]
             + hv.z * w2r[k4 * 4 + 2] + hv.w * w2r[k4 * 4 + 3];
      }
      x2c[n] = acc;
    }
  }
  PHASE_FENCE();
  if (wid == 0) {
    if (lane < 56) {            // logits2 (u2 row from global/L2, float4)
      const int n = lane >> 2, h = (lane >> 1) & 1, sd = lane & 1;
      const float* uu = uvec + (sd ? U_UD2 : U_US2) + h * HID1;
      float s = 0.f;
#pragma unroll
      for (int k4 = 0; k4 < 8; ++k4) {
        const float4 hv = *(const float4*)&h1s[n * H1_S + k4 * 4];
        const float4 uv = *(const float4*)&uu[k4 * 4];
        s += hv.x * uv.x + hv.y * uv.y + hv.z * uv.z + hv.w * uv.w;
      }
      (sd ? ald : als)[n * 2 + h] = s;
    }
    if (lane < NODES * 2) {     // softmax2 -> transposed wt writes
      const int h = lane & 1;
      const float ad = ald[lane];
      float a[NODES]; float m = -1e30f;
#pragma unroll
      for (int i = 0; i < NODES; ++i) {
        float v = als[i * 2 + h] + ad;
        v = v > 0.f ? v : SLOPE * v;
        a[i] = v; m = fmaxf(m, v);
      }
      float den = 0.f;
#pragma unroll
      for (int i = 0; i < NODES; ++i) { a[i] = __expf(a[i] - m); den += a[i]; }
      const float r = 1.f / den;
      float* wr = &wt[lane * 16];
      *(float4*)&wr[0]  = make_float4(a[0]*r,  a[1]*r,  a[2]*r,  a[3]*r);
      *(float4*)&wr[4]  = make_float4(a[4]*r,  a[5]*r,  a[6]*r,  a[7]*r);
      *(float4*)&wr[8]  = make_float4(a[8]*r,  a[9]*r,  a[10]*r, a[11]*r);
      *(float2*)&wr[12] = make_float2(a[12]*r, a[13]*r);
    }
  }
  // Wf1 first-half prefetch for MLP1 (112 lanes), issued before barrier
  float wf[32];
  if (tid < NODES * 8) {
    const int k = tid >> 3, e = tid & 7;
#pragma unroll
    for (int f = 0; f < 32; ++f) wf[f] = Wf1[(k * HID2 + f) * 8 + e];
  }
  __syncthreads();              // B3: wt + x2c ready
  PHASE_FENCE();

  // ---- P4: agg2 — head=wid; float4 wt broadcasts; LDS combine ----
  {
    float agg[NODES];
#pragma unroll
    for (int n = 0; n < NODES; ++n) {
      const float* wr = &wt[(n * 2 + wid) * 16];
      const float4 w0 = *(const float4*)&wr[0];
      const float4 w1 = *(const float4*)&wr[4];
      const float4 w2 = *(const float4*)&wr[8];
      const float2 w3 = *(const float2*)&wr[12];
      agg[n] = w0.x*x2c[0] + w0.y*x2c[1] + w0.z*x2c[2] + w0.w*x2c[3]
             + w1.x*x2c[4] + w1.y*x2c[5] + w1.z*x2c[6] + w1.w*x2c[7]
             + w2.x*x2c[8] + w2.y*x2c[9] + w2.z*x2c[10] + w2.w*x2c[11]
             + w3.x*x2c[12] + w3.y*x2c[13];
    }
    if (wid == 1) {
#pragma unroll
      for (int n = 0; n < NODES; ++n) h2s[n * H2_S + lane] = agg[n];
    }
    __syncthreads();            // B4
    if (wid == 0) {
      const float bb = b2[lane];
#pragma unroll
      for (int n = 0; n < NODES; ++n)
        h2s[n * H2_S + lane] = 0.5f * (agg[n] + h2s[n * H2_S + lane]) + bb;
    }
  }
  __syncthreads();              // B5: h2s ready
  PHASE_FENCE();

  // ---- P5: MLP1 (112 lanes; float4 h2s reads; first 32 f prefetched) ----
  if (tid < NODES * 8) {
    const int k = tid >> 3, e = tid & 7;
    float acc = bf1[k * 8 + e];
#pragma unroll
    for (int f4 = 0; f4 < 8; ++f4) {
      const float4 hv = *(const float4*)&h2s[k * H2_S + f4 * 4];
      acc += hv.x * wf[f4 * 4 + 0] + hv.y * wf[f4 * 4 + 1]
           + hv.z * wf[f4 * 4 + 2] + hv.w * wf[f4 * 4 + 3];
    }
#pragma unroll
    for (int f4 = 8; f4 < 16; ++f4) {
      const float4 hv = *(const float4*)&h2s[k * H2_S + f4 * 4];
      acc += hv.x * Wf1[(k * HID2 + f4 * 4 + 0) * 8 + e]
           + hv.y * Wf1[(k * HID2 + f4 * 4 + 1) * 8 + e]
           + hv.z * Wf1[(k * HID2 + f4 * 4 + 2) * 8 + e]
           + hv.w * Wf1[(k * HID2 + f4 * 4 + 3) * 8 + e];
    }
    hhs[tid] = fmaxf(acc, 0.f);
  }
  __syncthreads();              // B6: hhs ready
  PHASE_FENCE();

  // ---- P6: MLP2 (336 outputs; float4 hhs reads) ----
  for (int idx = tid; idx < NODES * OUT_F; idx += 128) {
    const int k = idx / OUT_F, o = idx - k * OUT_F;
    const float4 h0 = *(const float4*)&hhs[k * 8];
    const float4 h1 = *(const float4*)&hhs[k * 8 + 4];
    float acc = bf2[k * OUT_F + o]
              + h0.x * Wf2[(k * 8 + 0) * OUT_F + o]
              + h0.y * Wf2[(k * 8 + 1) * OUT_F + o]
              + h0.z * Wf2[(k * 8 + 2) * OUT_F + o]
              + h0.w * Wf2[(k * 8 + 3) * OUT_F + o]
              + h1.x * Wf2[(k * 8 + 4) * OUT_F + o]
              + h1.y * Wf2[(k * 8 + 5) * OUT_F + o]
              + h1.z * Wf2[(k * 8 + 6) * OUT_F + o]
              + h1.w * Wf2[(k * 8 + 7) * OUT_F + o];
    out[(size_t)k * ngraphs * OUT_F + (size_t)g * OUT_F + o] =
        1.f / (1.f + __expf(-acc));
  }
}

extern "C" void kernel_launch(void* const* d_in, const int* in_sizes, int n_in,
                              void* d_out, int out_size, void* d_ws, size_t ws_size,
                              hipStream_t stream) {
  const float* x      = (const float*)d_in[0];
  const float* y      = (const float*)d_in[1];
  // d_in[2] = edge_index, d_in[3] = batch : structure fixed, unused
  const float* W1     = (const float*)d_in[4];
  const float* a_src1 = (const float*)d_in[5];
  const float* a_dst1 = (const float*)d_in[6];
  const float* b1     = (const float*)d_in[7];
  const float* W2     = (const float*)d_in[8];
  const float* a_src2 = (const float*)d_in[9];
  const float* a_dst2 = (const float*)d_in[10];
  const float* b2     = (const float*)d_in[11];
  const float* Wf1    = (const float*)d_in[12];
  const float* bf1    = (const float*)d_in[13];
  const float* Wf2    = (const float*)d_in[14];
  const float* bf2    = (const float*)d_in[15];
  float* out = (float*)d_out;
  float* u   = (float*)d_ws;

  const int nnodes  = in_sizes[0] / IN_F;
  const int ngraphs = nnodes / NODES;

  hipLaunchKernelGGL(compute_uvecs, dim3(1), dim3(256), 0, stream,
                     W1, a_src1, a_dst1, W2, a_src2, a_dst2, u);
  hipLaunchKernelGGL(gnn_fused, dim3(ngraphs), dim3(128), 0, stream,
                     x, y, W1, b1, W2, b2, Wf1, bf1, Wf2, bf2, u, out, ngraphs);
}